// Round 3
// baseline (222.502 us; speedup 1.0000x reference)
//
#include <hip/hip_runtime.h>

#define CROP_H 14
#define CROP_W 14
#define IMG_B 8
#define IMG_C 256
#define IMG_H 100
#define IMG_W 152
#define NBOX 1000
#define PLANE (IMG_H * IMG_W)                 // 15200
#define POS (CROP_H * CROP_W)                 // 196
#define OUT_PER_BOX (IMG_C * POS)             // 50176
#define CG 32                                 // channels per block
#define NCG (IMG_C / CG)                      // 8 channel-groups per box (== #XCDs)

// ---------------------------------------------------------------------------
// Kernel A: stable counting-sort of boxes by box_ind -> perm (in d_ws).
// Deterministic: rank computed by scanning, no atomics.
// ---------------------------------------------------------------------------
__global__ __launch_bounds__(1024) void sort_boxes_kernel(
    const int* __restrict__ box_ind,
    int* __restrict__ perm)
{
    __shared__ int s_ind[NBOX];
    const int tid = threadIdx.x;
    for (int i = tid; i < NBOX; i += 1024) s_ind[i] = box_ind[i];
    __syncthreads();

    if (tid < NBOX) {
        const int mine = s_ind[tid];
        int pos = 0;
        for (int j = 0; j < NBOX; ++j) {
            const int v = s_ind[j];
            // elements strictly before mine in sorted order:
            //   v < mine, or (v == mine and j < tid)  [stable]
            pos += (v < mine) || ((v == mine) && (j < tid));
        }
        perm[pos] = tid;
    }
}

// ---------------------------------------------------------------------------
// Kernel B: crop-and-resize. bid%8 selects the channel group (== XCD under
// round-robin dispatch) so each XCD touches a single 32-channel slice; bid/8
// walks boxes in image-sorted order so the per-XCD L2 working set is ~2 MB.
// ---------------------------------------------------------------------------
__global__ __launch_bounds__(256) void CropAndResize_16630113370849_kernel(
    const float* __restrict__ image,
    const float* __restrict__ boxes,
    const int* __restrict__ box_ind,
    const int* __restrict__ perm,
    float* __restrict__ out)
{
    __shared__ int   s_offTL[POS], s_offTR[POS], s_offBL[POS], s_offBR[POS];
    __shared__ float s_xw[POS], s_yw[POS];
    __shared__ int   s_val[POS];
    __shared__ int   s_b;

    const int bid  = blockIdx.x;
    const int cg   = bid & 7;          // channel group == XCD (round-robin)
    const int slot = bid >> 3;         // 0..999, image-sorted box order
    const int n    = perm[slot];
    const int tid  = threadIdx.x;

    if (tid == 0) s_b = box_ind[n];

    if (tid < POS) {
        const int y = tid / CROP_W;
        const int x = tid - y * CROP_W;

        const float y1 = boxes[n * 4 + 0];
        const float x1 = boxes[n * 4 + 1];
        const float y2 = boxes[n * 4 + 2];
        const float x2 = boxes[n * 4 + 3];

        // exact fp32 round-to-nearest, no FMA — must match numpy bitwise for
        // the discontinuous validity test
        const float hs   = __fdiv_rn(__fmul_rn(__fsub_rn(y2, y1), (float)(IMG_H - 1)),
                                     (float)(CROP_H - 1));
        const float in_y = __fadd_rn(__fmul_rn(y1, (float)(IMG_H - 1)),
                                     __fmul_rn((float)y, hs));
        const int vy = (in_y >= 0.0f) && (in_y <= (float)(IMG_H - 1));
        const float top = floorf(in_y);
        const float ylp = __fsub_rn(in_y, top);
        const int ti = (int)fminf(fmaxf(top, 0.0f), (float)(IMG_H - 1));
        const int bi = (int)fminf(fmaxf(__fadd_rn(top, 1.0f), 0.0f), (float)(IMG_H - 1));

        const float ws   = __fdiv_rn(__fmul_rn(__fsub_rn(x2, x1), (float)(IMG_W - 1)),
                                     (float)(CROP_W - 1));
        const float in_x = __fadd_rn(__fmul_rn(x1, (float)(IMG_W - 1)),
                                     __fmul_rn((float)x, ws));
        const int vx = (in_x >= 0.0f) && (in_x <= (float)(IMG_W - 1));
        const float left = floorf(in_x);
        const float xlp = __fsub_rn(in_x, left);
        const int li = (int)fminf(fmaxf(left, 0.0f), (float)(IMG_W - 1));
        const int ri = (int)fminf(fmaxf(__fadd_rn(left, 1.0f), 0.0f), (float)(IMG_W - 1));

        s_offTL[tid] = ti * IMG_W + li;
        s_offTR[tid] = ti * IMG_W + ri;
        s_offBL[tid] = bi * IMG_W + li;
        s_offBR[tid] = bi * IMG_W + ri;
        s_xw[tid] = xlp;
        s_yw[tid] = ylp;
        s_val[tid] = vy & vx;
    }
    __syncthreads();

    const float* __restrict__ img_b =
        image + (size_t)s_b * (size_t)(IMG_C * PLANE) + (size_t)(cg * CG) * PLANE;
    float* __restrict__ out_n =
        out + (size_t)n * (size_t)OUT_PER_BOX + (size_t)(cg * CG) * POS;

    // branchless: loads are always in-bounds (clamped offsets); validity only
    // selects the final value -> compiler can batch loads across the unroll.
    #pragma unroll 4
    for (int idx = tid; idx < CG * POS; idx += 256) {
        const int cl = idx / POS;         // constant divisor -> magic mul
        const int p  = idx - cl * POS;

        const float* __restrict__ pl = img_b + cl * PLANE;
        const float tl = pl[s_offTL[p]];
        const float tr = pl[s_offTR[p]];
        const float bl = pl[s_offBL[p]];
        const float br = pl[s_offBR[p]];
        const float xw = s_xw[p], yw = s_yw[p];
        const float top_v = __fadd_rn(tl, __fmul_rn(__fsub_rn(tr, tl), xw));
        const float bot_v = __fadd_rn(bl, __fmul_rn(__fsub_rn(br, bl), xw));
        const float v = __fadd_rn(top_v, __fmul_rn(__fsub_rn(bot_v, top_v), yw));
        out_n[idx] = s_val[p] ? v : 0.0f;
    }
}

extern "C" void kernel_launch(void* const* d_in, const int* in_sizes, int n_in,
                              void* d_out, int out_size, void* d_ws, size_t ws_size,
                              hipStream_t stream) {
    const float* image  = (const float*)d_in[0];
    const float* boxes  = (const float*)d_in[1];
    const int*   boxind = (const int*)d_in[2];
    float* out = (float*)d_out;
    int* perm = (int*)d_ws;

    sort_boxes_kernel<<<1, 1024, 0, stream>>>(boxind, perm);

    dim3 grid(NBOX * NCG);
    dim3 block(256);
    CropAndResize_16630113370849_kernel<<<grid, block, 0, stream>>>(
        image, boxes, boxind, perm, out);
}

// Round 4
// 142.159 us; speedup vs baseline: 1.5652x; 1.5652x over previous
//
#include <hip/hip_runtime.h>

#define CROP_H 14
#define CROP_W 14
#define IMG_B 8
#define IMG_C 256
#define IMG_H 100
#define IMG_W 152
#define NBOX 1000
#define PLANE (IMG_H * IMG_W)                 // 15200
#define POS (CROP_H * CROP_W)                 // 196
#define OUT_PER_BOX (IMG_C * POS)             // 50176
#define CG 32                                 // channels per block
#define NCG (IMG_C / CG)                      // 8 channel-groups per box (== #XCDs)

typedef float f2u __attribute__((ext_vector_type(2), aligned(4)));

// ---------------------------------------------------------------------------
// Kernel A: stable counting-sort of boxes by box_ind -> perm, via per-key
// bitmasks + popcount ranks. Deterministic (atomicOr is order-independent).
// ---------------------------------------------------------------------------
__global__ __launch_bounds__(1024) void sort_boxes_kernel(
    const int* __restrict__ box_ind,
    int* __restrict__ perm)
{
    __shared__ unsigned s_mask[IMG_B][32];     // 8 keys x 1000 bits
    __shared__ int s_tot[IMG_B];
    const int tid = threadIdx.x;

    if (tid < IMG_B * 32) ((unsigned*)s_mask)[tid] = 0u;
    __syncthreads();

    int key = 0;
    if (tid < NBOX) {
        key = box_ind[tid];
        atomicOr(&s_mask[key][tid >> 5], 1u << (tid & 31));
    }
    __syncthreads();

    if (tid < IMG_B) {
        int t = 0;
        #pragma unroll
        for (int w = 0; w < 32; ++w) t += __popc(s_mask[tid][w]);
        s_tot[tid] = t;
    }
    __syncthreads();

    if (tid < NBOX) {
        int base = 0;
        #pragma unroll
        for (int k = 0; k < IMG_B; ++k) base += (k < key) ? s_tot[k] : 0;
        const int w = tid >> 5, b = tid & 31;
        int r = __popc(s_mask[key][w] & ((b == 0) ? 0u : ((1u << b) - 1u)));
        for (int ww = 0; ww < w; ++ww) r += __popc(s_mask[key][ww]);
        perm[base + r] = tid;
    }
}

// ---------------------------------------------------------------------------
// Kernel B: crop-and-resize. bid%8 = channel group (== XCD under round-robin
// dispatch); bid/8 walks boxes in image-sorted order -> per-XCD L2 working
// set ~2 MB. Gather = two adjacent-pair float2 loads per output (corner
// offsets collapse because ri=li+1 / bi=ti+1 except at the clamp edge, which
// reduces to a select).
// ---------------------------------------------------------------------------
__global__ __launch_bounds__(256) void CropAndResize_16630113370849_kernel(
    const float* __restrict__ image,
    const float* __restrict__ boxes,
    const int* __restrict__ box_ind,
    const int* __restrict__ perm,
    int use_perm,
    float* __restrict__ out)
{
    __shared__ int   s_pack[POS];
    __shared__ float s_xw[POS], s_yw[POS];
    __shared__ int   s_b;

    const int bid  = blockIdx.x;
    const int cg   = bid & 7;
    const int slot = bid >> 3;
    const int n    = use_perm ? perm[slot] : slot;
    const int tid  = threadIdx.x;

    if (tid == 0) s_b = box_ind[n];

    if (tid < POS) {
        const int y = tid / CROP_W;
        const int x = tid - y * CROP_W;

        const float y1 = boxes[n * 4 + 0];
        const float x1 = boxes[n * 4 + 1];
        const float y2 = boxes[n * 4 + 2];
        const float x2 = boxes[n * 4 + 3];

        // exact fp32 round-to-nearest, no FMA — must match numpy bitwise for
        // the discontinuous validity test
        const float hs   = __fdiv_rn(__fmul_rn(__fsub_rn(y2, y1), (float)(IMG_H - 1)),
                                     (float)(CROP_H - 1));
        const float in_y = __fadd_rn(__fmul_rn(y1, (float)(IMG_H - 1)),
                                     __fmul_rn((float)y, hs));
        const int vy = (in_y >= 0.0f) && (in_y <= (float)(IMG_H - 1));
        const float top = floorf(in_y);
        const float ylp = __fsub_rn(in_y, top);
        const int ti = (int)fminf(fmaxf(top, 0.0f), (float)(IMG_H - 1));

        const float ws   = __fdiv_rn(__fmul_rn(__fsub_rn(x2, x1), (float)(IMG_W - 1)),
                                     (float)(CROP_W - 1));
        const float in_x = __fadd_rn(__fmul_rn(x1, (float)(IMG_W - 1)),
                                     __fmul_rn((float)x, ws));
        const int vx = (in_x >= 0.0f) && (in_x <= (float)(IMG_W - 1));
        const float left = floorf(in_x);
        const float xlp = __fsub_rn(in_x, left);
        const int li = (int)fminf(fmaxf(left, 0.0f), (float)(IMG_W - 1));

        // 2x2 block base: rows r0=min(ti,98), r0+1; cols c0=min(li,150), c0+1
        // top row is r0 unless ti==99 (bottom clamp): then both rows = 99.
        // left col is c0 unless li==151 (right clamp): then both cols = 151.
        const int r0   = min(ti, IMG_H - 2);
        const int c0   = min(li, IMG_W - 2);
        const int sely = (ti == IMG_H - 1);
        const int selx = (li == IMG_W - 1);
        const int off  = r0 * IMG_W + c0;       // < 15046, fits 14 bits

        s_pack[tid] = off | (selx << 14) | (sely << 15) | ((vy & vx) << 16);
        s_xw[tid] = xlp;
        s_yw[tid] = ylp;
    }
    __syncthreads();

    const float* __restrict__ img_cg =
        image + (size_t)s_b * (size_t)(IMG_C * PLANE) + (size_t)(cg * CG) * PLANE;
    float* __restrict__ out_n =
        out + (size_t)n * (size_t)OUT_PER_BOX + (size_t)(cg * CG) * POS;

    #pragma unroll 4
    for (int k = 0; k < 24; ++k) {
        const int idx = (k << 8) + tid;
        const int cl = idx / POS;               // magic mul
        const int p  = idx - cl * POS;

        const int w = s_pack[p];
        const float* pl = img_cg + cl * PLANE + (w & 0x3FFF);
        const f2u ra = *(const f2u*)(pl);
        const f2u rb = *(const f2u*)(pl + IMG_W);

        const float tA = (w & 0x8000) ? rb.x : ra.x;   // top-left candidate
        const float tB = (w & 0x8000) ? rb.y : ra.y;   // top-right
        const float tl = (w & 0x4000) ? tB : tA;
        const float tr = tB;
        const float bl = (w & 0x4000) ? rb.y : rb.x;
        const float br = rb.y;

        const float xw = s_xw[p], yw = s_yw[p];
        const float top_v = __fadd_rn(tl, __fmul_rn(__fsub_rn(tr, tl), xw));
        const float bot_v = __fadd_rn(bl, __fmul_rn(__fsub_rn(br, bl), xw));
        const float v = __fadd_rn(top_v, __fmul_rn(__fsub_rn(bot_v, top_v), yw));
        out_n[idx] = (w & 0x10000) ? v : 0.0f;
    }
    // tail: 6272 = 24.5 * 256
    if (tid < 128) {
        const int idx = 24 * 256 + tid;
        const int cl = idx / POS;
        const int p  = idx - cl * POS;

        const int w = s_pack[p];
        const float* pl = img_cg + cl * PLANE + (w & 0x3FFF);
        const f2u ra = *(const f2u*)(pl);
        const f2u rb = *(const f2u*)(pl + IMG_W);

        const float tA = (w & 0x8000) ? rb.x : ra.x;
        const float tB = (w & 0x8000) ? rb.y : ra.y;
        const float tl = (w & 0x4000) ? tB : tA;
        const float tr = tB;
        const float bl = (w & 0x4000) ? rb.y : rb.x;
        const float br = rb.y;

        const float xw = s_xw[p], yw = s_yw[p];
        const float top_v = __fadd_rn(tl, __fmul_rn(__fsub_rn(tr, tl), xw));
        const float bot_v = __fadd_rn(bl, __fmul_rn(__fsub_rn(br, bl), xw));
        const float v = __fadd_rn(top_v, __fmul_rn(__fsub_rn(bot_v, top_v), yw));
        out_n[idx] = (w & 0x10000) ? v : 0.0f;
    }
}

extern "C" void kernel_launch(void* const* d_in, const int* in_sizes, int n_in,
                              void* d_out, int out_size, void* d_ws, size_t ws_size,
                              hipStream_t stream) {
    const float* image  = (const float*)d_in[0];
    const float* boxes  = (const float*)d_in[1];
    const int*   boxind = (const int*)d_in[2];
    float* out = (float*)d_out;

    const int use_perm = (ws_size >= (size_t)(NBOX * sizeof(int))) ? 1 : 0;
    int* perm = (int*)d_ws;

    if (use_perm) {
        sort_boxes_kernel<<<1, 1024, 0, stream>>>(boxind, perm);
    }

    dim3 grid(NBOX * NCG);
    dim3 block(256);
    CropAndResize_16630113370849_kernel<<<grid, block, 0, stream>>>(
        image, boxes, boxind, perm, use_perm, out);
}

// Round 5
// 104.033 us; speedup vs baseline: 2.1388x; 1.3665x over previous
//
#include <hip/hip_runtime.h>

#define CROP_H 14
#define CROP_W 14
#define IMG_B 8
#define IMG_C 256
#define IMG_H 100
#define IMG_W 152
#define NBOX 1000
#define PLANE (IMG_H * IMG_W)                 // 15200
#define POS (CROP_H * CROP_W)                 // 196
#define OUT_PER_BOX (IMG_C * POS)             // 50176
#define CG 32                                 // channels per block
#define NCG (IMG_C / CG)                      // 8 channel-groups per box (== #XCDs)

typedef float f2u __attribute__((ext_vector_type(2), aligned(4)));

// ---------------------------------------------------------------------------
// Kernel A: stable counting-sort of boxes by box_ind -> perm, via per-key
// bitmasks + popcount ranks. Deterministic (atomicOr is order-independent).
// ---------------------------------------------------------------------------
__global__ __launch_bounds__(1024) void sort_boxes_kernel(
    const int* __restrict__ box_ind,
    int* __restrict__ perm)
{
    __shared__ unsigned s_mask[IMG_B][32];     // 8 keys x 1000 bits
    __shared__ int s_tot[IMG_B];
    const int tid = threadIdx.x;

    if (tid < IMG_B * 32) ((unsigned*)s_mask)[tid] = 0u;
    __syncthreads();

    int key = 0;
    if (tid < NBOX) {
        key = box_ind[tid];
        atomicOr(&s_mask[key][tid >> 5], 1u << (tid & 31));
    }
    __syncthreads();

    if (tid < IMG_B) {
        int t = 0;
        #pragma unroll
        for (int w = 0; w < 32; ++w) t += __popc(s_mask[tid][w]);
        s_tot[tid] = t;
    }
    __syncthreads();

    if (tid < NBOX) {
        int base = 0;
        #pragma unroll
        for (int k = 0; k < IMG_B; ++k) base += (k < key) ? s_tot[k] : 0;
        const int w = tid >> 5, b = tid & 31;
        int r = __popc(s_mask[key][w] & ((b == 0) ? 0u : ((1u << b) - 1u)));
        for (int ww = 0; ww < w; ++ww) r += __popc(s_mask[key][ww]);
        perm[base + r] = tid;
    }
}

// ---------------------------------------------------------------------------
// Kernel B: crop-and-resize, register-resident interpolation state.
// One thread = one crop position (tid < 196); loops over the 32 channels of
// its channel-group. No LDS, no syncthreads; loop body = 2 adjacent-pair
// float2 loads (pure pointer increment) + lerp + coalesced nt store.
// bid%8 = channel group (== XCD under round-robin dispatch); bid/8 walks
// boxes in image-sorted order -> per-XCD L2 working set ~2 MB.
// ---------------------------------------------------------------------------
__global__ __launch_bounds__(256) void CropAndResize_16630113370849_kernel(
    const float* __restrict__ image,
    const float* __restrict__ boxes,
    const int* __restrict__ box_ind,
    const int* __restrict__ perm,
    int use_perm,
    float* __restrict__ out)
{
    const int bid  = blockIdx.x;
    const int cg   = bid & 7;
    const int slot = bid >> 3;
    const int tid  = threadIdx.x;
    if (tid >= POS) return;

    const int n = use_perm ? perm[slot] : slot;
    const int b = box_ind[n];                  // wave-uniform -> scalarized

    const int y = tid / CROP_W;                // magic mul
    const int x = tid - y * CROP_W;

    const float y1 = boxes[n * 4 + 0];
    const float x1 = boxes[n * 4 + 1];
    const float y2 = boxes[n * 4 + 2];
    const float x2 = boxes[n * 4 + 3];

    // exact fp32 round-to-nearest, no FMA — must match numpy bitwise for the
    // discontinuous validity test
    const float hs   = __fdiv_rn(__fmul_rn(__fsub_rn(y2, y1), (float)(IMG_H - 1)),
                                 (float)(CROP_H - 1));
    const float in_y = __fadd_rn(__fmul_rn(y1, (float)(IMG_H - 1)),
                                 __fmul_rn((float)y, hs));
    const int vy = (in_y >= 0.0f) && (in_y <= (float)(IMG_H - 1));
    const float top = floorf(in_y);
    const float yw  = __fsub_rn(in_y, top);
    const int ti = (int)fminf(fmaxf(top, 0.0f), (float)(IMG_H - 1));

    const float ws   = __fdiv_rn(__fmul_rn(__fsub_rn(x2, x1), (float)(IMG_W - 1)),
                                 (float)(CROP_W - 1));
    const float in_x = __fadd_rn(__fmul_rn(x1, (float)(IMG_W - 1)),
                                 __fmul_rn((float)x, ws));
    const int vx = (in_x >= 0.0f) && (in_x <= (float)(IMG_W - 1));
    const float left = floorf(in_x);
    const float xw   = __fsub_rn(in_x, left);
    const int li = (int)fminf(fmaxf(left, 0.0f), (float)(IMG_W - 1));

    // 2x2 block base: rows r0=min(ti,98), r0+1; cols c0=min(li,150), c0+1.
    // ti==99 (bottom clamp) -> both rows are row 99 (sely);
    // li==151 (right clamp) -> both cols are col 151 (selx).
    const int r0   = min(ti, IMG_H - 2);
    const int c0   = min(li, IMG_W - 2);
    const bool sely = (ti == IMG_H - 1);
    const bool selx = (li == IMG_W - 1);
    const bool vald = (vy & vx) != 0;

    const float* __restrict__ pl =
        image + (size_t)b * (size_t)(IMG_C * PLANE)
              + (size_t)(cg * CG) * PLANE + (r0 * IMG_W + c0);
    float* __restrict__ po =
        out + (size_t)n * (size_t)OUT_PER_BOX + (size_t)(cg * CG) * POS + tid;

    #pragma unroll 8
    for (int cl = 0; cl < CG; ++cl) {
        const f2u ra = *(const f2u*)(pl);
        const f2u rb = *(const f2u*)(pl + IMG_W);

        const float tA = sely ? rb.x : ra.x;   // top-left candidate
        const float tB = sely ? rb.y : ra.y;   // top-right
        const float tl = selx ? tB : tA;
        const float bl = selx ? rb.y : rb.x;

        const float top_v = __fadd_rn(tl, __fmul_rn(__fsub_rn(tB, tl), xw));
        const float bot_v = __fadd_rn(bl, __fmul_rn(__fsub_rn(rb.y, bl), xw));
        const float v = __fadd_rn(top_v, __fmul_rn(__fsub_rn(bot_v, top_v), yw));

        __builtin_nontemporal_store(vald ? v : 0.0f, po);
        pl += PLANE;
        po += POS;
    }
}

extern "C" void kernel_launch(void* const* d_in, const int* in_sizes, int n_in,
                              void* d_out, int out_size, void* d_ws, size_t ws_size,
                              hipStream_t stream) {
    const float* image  = (const float*)d_in[0];
    const float* boxes  = (const float*)d_in[1];
    const int*   boxind = (const int*)d_in[2];
    float* out = (float*)d_out;

    const int use_perm = (ws_size >= (size_t)(NBOX * sizeof(int))) ? 1 : 0;
    int* perm = (int*)d_ws;

    if (use_perm) {
        sort_boxes_kernel<<<1, 1024, 0, stream>>>(boxind, perm);
    }

    dim3 grid(NBOX * NCG);
    dim3 block(256);
    CropAndResize_16630113370849_kernel<<<grid, block, 0, stream>>>(
        image, boxes, boxind, perm, use_perm, out);
}